// Round 1
// baseline (1104.378 us; speedup 1.0000x reference)
//
#include <hip/hip_runtime.h>

#define N_NODES 50000
#define NGRAPH 64
#define HID 128
#define NLAYERS 4

// ---------------- init: zero histogram + pooling accumulators ----------------
__global__ void k_init(int* __restrict__ cnt, float* __restrict__ psum, float* __restrict__ pcnt) {
  int i = blockIdx.x * blockDim.x + threadIdx.x;
  if (i < N_NODES) cnt[i] = 0;
  if (i < NGRAPH * HID) psum[i] = 0.f;
  if (i < NGRAPH) pcnt[i] = 0.f;
}

// ---------------- in-degree histogram over target (col) ----------------
__global__ void k_hist(const int* __restrict__ col, int E, int* __restrict__ cnt) {
  int e = blockIdx.x * blockDim.x + threadIdx.x;
  if (e < E) atomicAdd(&cnt[col[e]], 1);
}

// ---------------- single-block exclusive scan -> offsets, cursor, dinv ----------------
__global__ __launch_bounds__(512) void k_scan(const int* __restrict__ cnt, int* __restrict__ offs,
                                              int* __restrict__ cursor, float* __restrict__ dinv) {
  __shared__ int part[512];
  const int t = threadIdx.x;
  const int CH = (N_NODES + 511) / 512;  // 98
  const int lo = t * CH;
  const int hi = min(lo + CH, N_NODES);
  int s = 0;
  for (int i = lo; i < hi; ++i) s += cnt[i];
  part[t] = s;
  __syncthreads();
  // inclusive Hillis-Steele scan over 512 partials
  for (int off = 1; off < 512; off <<= 1) {
    int v = (t >= off) ? part[t - off] : 0;
    __syncthreads();
    part[t] += v;
    __syncthreads();
  }
  int base = (t == 0) ? 0 : part[t - 1];
  for (int i = lo; i < hi; ++i) {
    int c = cnt[i];
    offs[i] = base;
    cursor[i] = base;
    base += c;
    // self-loop included in degree; deg >= 1 always
    dinv[i] = 1.0f / sqrtf((float)(c + 1));
  }
  if (t == 511) offs[N_NODES] = part[511];
}

// ---------------- scatter edges into CSR buckets (by target) ----------------
__global__ void k_fill(const int* __restrict__ row, const int* __restrict__ col, int E,
                       const float* __restrict__ dinv, int* __restrict__ cursor,
                       int* __restrict__ csr_src, float* __restrict__ csr_w) {
  int e = blockIdx.x * blockDim.x + threadIdx.x;
  if (e >= E) return;
  int r = row[e], c = col[e];
  int pos = atomicAdd(&cursor[c], 1);
  csr_src[pos] = r;
  csr_w[pos] = dinv[r] * dinv[c];
}

// ---------------- f32 GEMM: Y[M,128] = X[M,128] @ W[128,128] (+bias)(+relu) ----------------
// 64-row tile in LDS, 256 threads, each thread computes 8 rows x 4 cols.
template <bool BIAS, bool RELU>
__global__ __launch_bounds__(256) void k_gemm(const float* __restrict__ X, const float* __restrict__ W,
                                              const float* __restrict__ bias, float* __restrict__ Y, int M) {
  __shared__ float xs[64 * HID];  // 32 KB
  float4* xs4 = (float4*)xs;
  const float4* X4 = (const float4*)X;
  const float4* W4 = (const float4*)W;
  const int tid = threadIdx.x;
  const int rbase = blockIdx.x * 64;

#pragma unroll
  for (int t = 0; t < 8; ++t) {
    int idx = t * 256 + tid;        // 0..2047
    int r = idx >> 5, c4 = idx & 31;
    int gr = rbase + r;
    float4 v = make_float4(0.f, 0.f, 0.f, 0.f);
    if (gr < M) v = X4[(size_t)gr * 32 + c4];
    xs4[idx] = v;                   // idx == r*32 + c4
  }
  __syncthreads();

  const int tc = tid & 31;   // column group: cols tc*4 .. tc*4+3
  const int tr = tid >> 5;   // row group:    rows tr*8 .. tr*8+7
  const int r0 = tr * 8;

  float acc[8][4];
#pragma unroll
  for (int i = 0; i < 8; ++i)
#pragma unroll
    for (int c = 0; c < 4; ++c) acc[i][c] = 0.f;

  for (int k4 = 0; k4 < 32; ++k4) {
    float4 w0 = W4[(k4 * 4 + 0) * 32 + tc];
    float4 w1 = W4[(k4 * 4 + 1) * 32 + tc];
    float4 w2 = W4[(k4 * 4 + 2) * 32 + tc];
    float4 w3 = W4[(k4 * 4 + 3) * 32 + tc];
#pragma unroll
    for (int i = 0; i < 8; ++i) {
      float4 xv = xs4[(r0 + i) * 32 + k4];
      acc[i][0] += xv.x * w0.x + xv.y * w1.x + xv.z * w2.x + xv.w * w3.x;
      acc[i][1] += xv.x * w0.y + xv.y * w1.y + xv.z * w2.y + xv.w * w3.y;
      acc[i][2] += xv.x * w0.z + xv.y * w1.z + xv.z * w2.z + xv.w * w3.z;
      acc[i][3] += xv.x * w0.w + xv.y * w1.w + xv.z * w2.w + xv.w * w3.w;
    }
  }

  float4 bv = make_float4(0.f, 0.f, 0.f, 0.f);
  if (BIAS) bv = ((const float4*)bias)[tc];
#pragma unroll
  for (int i = 0; i < 8; ++i) {
    int gr = rbase + r0 + i;
    if (gr < M) {
      float4 o;
      o.x = acc[i][0] + bv.x;
      o.y = acc[i][1] + bv.y;
      o.z = acc[i][2] + bv.z;
      o.w = acc[i][3] + bv.w;
      if (RELU) {
        o.x = fmaxf(o.x, 0.f); o.y = fmaxf(o.y, 0.f);
        o.z = fmaxf(o.z, 0.f); o.w = fmaxf(o.w, 0.f);
      }
      ((float4*)Y)[(size_t)gr * 32 + tc] = o;
    }
  }
}

// ---------------- aggregation: out[v] = relu( sum_e w_e * hW[src_e] + dinv[v]^2 * hW[v] + b ) ----------------
__global__ __launch_bounds__(128) void k_agg(const float* __restrict__ hW, const int* __restrict__ offs,
                                             const int* __restrict__ csr_src, const float* __restrict__ csr_w,
                                             const float* __restrict__ dinv, const float* __restrict__ bias,
                                             float* __restrict__ out) {
  const int v = blockIdx.x;
  const int j = threadIdx.x;
  const float d = dinv[v];
  float acc = d * d * hW[(size_t)v * HID + j];  // self-loop message
  const int lo = offs[v], hi = offs[v + 1];
  for (int idx = lo; idx < hi; ++idx) {
    int s = csr_src[idx];
    float w = csr_w[idx];
    acc += w * hW[(size_t)s * HID + j];
  }
  out[(size_t)v * HID + j] = fmaxf(acc + bias[j], 0.f);
}

// ---------------- mean-pool accumulation (atomic) ----------------
__global__ void k_pool(const float* __restrict__ h, const int* __restrict__ batch,
                       float* __restrict__ psum, float* __restrict__ pcnt) {
  int gid = blockIdx.x * blockDim.x + threadIdx.x;
  if (gid >= N_NODES * HID) return;
  int v = gid >> 7, j = gid & 127;
  int b = batch[v];
  atomicAdd(&psum[b * HID + j], h[gid]);
  if (j == 0) atomicAdd(&pcnt[b], 1.f);
}

// ---------------- heads: out[t,g,:] = pooled[g] @ W_t + b_t ----------------
__global__ __launch_bounds__(128) void k_heads(const float* __restrict__ psum, const float* __restrict__ pcnt,
                                               const float* __restrict__ W0, const float* __restrict__ b0,
                                               const float* __restrict__ W1, const float* __restrict__ b1,
                                               const float* __restrict__ W2, const float* __restrict__ b2,
                                               float* __restrict__ out) {
  __shared__ float pm[HID];
  const int g = blockIdx.x, t = blockIdx.y, j = threadIdx.x;
  float c = fmaxf(pcnt[g], 1.f);
  pm[j] = psum[g * HID + j] / c;
  __syncthreads();
  const float* W = (t == 0) ? W0 : ((t == 1) ? W1 : W2);
  const float* b = (t == 0) ? b0 : ((t == 1) ? b1 : b2);
  float acc = 0.f;
#pragma unroll 8
  for (int k = 0; k < HID; ++k) acc += pm[k] * W[k * HID + j];
  out[((size_t)t * NGRAPH + g) * HID + j] = acc + b[j];
}

extern "C" void kernel_launch(void* const* d_in, const int* in_sizes, int n_in,
                              void* d_out, int out_size, void* d_ws, size_t ws_size,
                              hipStream_t stream) {
  const float* x     = (const float*)d_in[0];
  const int*   ei    = (const int*)d_in[1];
  const int*   batch = (const int*)d_in[2];
  const float* W_in  = (const float*)d_in[3];
  const float* b_in  = (const float*)d_in[4];
  const float* convW = (const float*)d_in[5];
  const float* convb = (const float*)d_in[6];
  const float* W_def = (const float*)d_in[7];
  const float* b_def = (const float*)d_in[8];
  const float* W_syn = (const float*)d_in[9];
  const float* b_syn = (const float*)d_in[10];
  const float* W_rel = (const float*)d_in[11];
  const float* b_rel = (const float*)d_in[12];

  const int E = in_sizes[1] / 2;  // 640000
  const int* row = ei;            // source
  const int* col = ei + E;        // target (aggregation index)

  char* base = (char*)d_ws;
  size_t off = 0;
  auto alloc = [&](size_t bytes) -> void* {
    void* p = base + off;
    off += (bytes + 255) & ~size_t(255);
    return p;
  };
  int*   cnt     = (int*)  alloc((size_t)N_NODES * 4);
  float* dinv    = (float*)alloc((size_t)N_NODES * 4);
  int*   offs    = (int*)  alloc((size_t)(N_NODES + 1) * 4);
  int*   cursor  = (int*)  alloc((size_t)N_NODES * 4);
  int*   csr_src = (int*)  alloc((size_t)E * 4);
  float* csr_w   = (float*)alloc((size_t)E * 4);
  float* hA      = (float*)alloc((size_t)N_NODES * HID * 4);
  float* hB      = (float*)alloc((size_t)N_NODES * HID * 4);
  float* psum    = (float*)alloc((size_t)NGRAPH * HID * 4);
  float* pcnt    = (float*)alloc((size_t)NGRAPH * 4);

  // graph preprocessing (per-call; deterministic up to f32 bucket order)
  k_init<<<(N_NODES + 255) / 256, 256, 0, stream>>>(cnt, psum, pcnt);
  k_hist<<<(E + 255) / 256, 256, 0, stream>>>(col, E, cnt);
  k_scan<<<1, 512, 0, stream>>>(cnt, offs, cursor, dinv);
  k_fill<<<(E + 255) / 256, 256, 0, stream>>>(row, col, E, dinv, cursor, csr_src, csr_w);

  const int gemm_grid = (N_NODES + 63) / 64;
  // h = relu(x @ W_in + b_in)
  k_gemm<true, true><<<gemm_grid, 256, 0, stream>>>(x, W_in, b_in, hA, N_NODES);

  for (int i = 0; i < NLAYERS; ++i) {
    k_gemm<false, false><<<gemm_grid, 256, 0, stream>>>(hA, convW + (size_t)i * HID * HID, nullptr, hB, N_NODES);
    k_agg<<<N_NODES, HID, 0, stream>>>(hB, offs, csr_src, csr_w, dinv, convb + (size_t)i * HID, hA);
  }

  k_pool<<<(N_NODES * HID + 255) / 256, 256, 0, stream>>>(hA, batch, psum, pcnt);
  k_heads<<<dim3(NGRAPH, 3), HID, 0, stream>>>(psum, pcnt, W_def, b_def, W_syn, b_syn, W_rel, b_rel,
                                               (float*)d_out);
}

// Round 2
// 997.169 us; speedup vs baseline: 1.1075x; 1.1075x over previous
//
#include <hip/hip_runtime.h>

#define N_NODES 50000
#define NGRAPH 64
#define HID 128
#define NLAYERS 4

// ---------------- init: zero histogram + graph bounds ----------------
__global__ void k_init(int* __restrict__ cnt, int* __restrict__ gstart, int* __restrict__ gend) {
  int i = blockIdx.x * blockDim.x + threadIdx.x;
  if (i < N_NODES) cnt[i] = 0;
  if (i < NGRAPH) { gstart[i] = N_NODES; gend[i] = 0; }
}

// ---------------- in-degree histogram over target (col) ----------------
__global__ void k_hist(const int* __restrict__ col, int E, int* __restrict__ cnt) {
  int e = blockIdx.x * blockDim.x + threadIdx.x;
  if (e < E) atomicAdd(&cnt[col[e]], 1);
}

// ---------------- graph boundaries (batch is sorted) ----------------
__global__ void k_bounds(const int* __restrict__ batch, int* __restrict__ gstart, int* __restrict__ gend) {
  int i = blockIdx.x * blockDim.x + threadIdx.x;
  if (i >= N_NODES) return;
  int b = batch[i];
  atomicMin(&gstart[b], i);
  atomicMax(&gend[b], i + 1);
}

// ---------------- single-block exclusive scan -> offsets, cursor, dinv ----------------
__global__ __launch_bounds__(512) void k_scan(const int* __restrict__ cnt, int* __restrict__ offs,
                                              int* __restrict__ cursor, float* __restrict__ dinv) {
  __shared__ int part[512];
  const int t = threadIdx.x;
  const int CH = (N_NODES + 511) / 512;  // 98
  const int lo = t * CH;
  const int hi = min(lo + CH, N_NODES);
  int s = 0;
  for (int i = lo; i < hi; ++i) s += cnt[i];
  part[t] = s;
  __syncthreads();
  for (int off = 1; off < 512; off <<= 1) {
    int v = (t >= off) ? part[t - off] : 0;
    __syncthreads();
    part[t] += v;
    __syncthreads();
  }
  int base = (t == 0) ? 0 : part[t - 1];
  for (int i = lo; i < hi; ++i) {
    int c = cnt[i];
    offs[i] = base;
    cursor[i] = base;
    base += c;
    dinv[i] = 1.0f / sqrtf((float)(c + 1));  // self-loop included in degree
  }
  if (t == 511) offs[N_NODES] = part[511];
}

// ---------------- scatter edges into CSR buckets (by target) ----------------
__global__ void k_fill(const int* __restrict__ row, const int* __restrict__ col, int E,
                       const float* __restrict__ dinv, int* __restrict__ cursor,
                       int* __restrict__ csr_src, float* __restrict__ csr_w) {
  int e = blockIdx.x * blockDim.x + threadIdx.x;
  if (e >= E) return;
  int r = row[e], c = col[e];
  int pos = atomicAdd(&cursor[c], 1);
  csr_src[pos] = r;
  csr_w[pos] = dinv[r] * dinv[c];
}

// ---------------- f32 GEMM: Y[M,128] = X[M,128] @ W[128,128] (+bias)(+relu) ----------------
template <bool BIAS, bool RELU>
__global__ __launch_bounds__(256) void k_gemm(const float* __restrict__ X, const float* __restrict__ W,
                                              const float* __restrict__ bias, float* __restrict__ Y, int M) {
  __shared__ float xs[64 * HID];  // 32 KB
  float4* xs4 = (float4*)xs;
  const float4* X4 = (const float4*)X;
  const float4* W4 = (const float4*)W;
  const int tid = threadIdx.x;
  const int rbase = blockIdx.x * 64;

#pragma unroll
  for (int t = 0; t < 8; ++t) {
    int idx = t * 256 + tid;
    int r = idx >> 5, c4 = idx & 31;
    int gr = rbase + r;
    float4 v = make_float4(0.f, 0.f, 0.f, 0.f);
    if (gr < M) v = X4[(size_t)gr * 32 + c4];
    xs4[idx] = v;
  }
  __syncthreads();

  const int tc = tid & 31;
  const int tr = tid >> 5;
  const int r0 = tr * 8;

  float acc[8][4];
#pragma unroll
  for (int i = 0; i < 8; ++i)
#pragma unroll
    for (int c = 0; c < 4; ++c) acc[i][c] = 0.f;

  for (int k4 = 0; k4 < 32; ++k4) {
    float4 w0 = W4[(k4 * 4 + 0) * 32 + tc];
    float4 w1 = W4[(k4 * 4 + 1) * 32 + tc];
    float4 w2 = W4[(k4 * 4 + 2) * 32 + tc];
    float4 w3 = W4[(k4 * 4 + 3) * 32 + tc];
#pragma unroll
    for (int i = 0; i < 8; ++i) {
      float4 xv = xs4[(r0 + i) * 32 + k4];
      acc[i][0] += xv.x * w0.x + xv.y * w1.x + xv.z * w2.x + xv.w * w3.x;
      acc[i][1] += xv.x * w0.y + xv.y * w1.y + xv.z * w2.y + xv.w * w3.y;
      acc[i][2] += xv.x * w0.z + xv.y * w1.z + xv.z * w2.z + xv.w * w3.z;
      acc[i][3] += xv.x * w0.w + xv.y * w1.w + xv.z * w2.w + xv.w * w3.w;
    }
  }

  float4 bv = make_float4(0.f, 0.f, 0.f, 0.f);
  if (BIAS) bv = ((const float4*)bias)[tc];
#pragma unroll
  for (int i = 0; i < 8; ++i) {
    int gr = rbase + r0 + i;
    if (gr < M) {
      float4 o;
      o.x = acc[i][0] + bv.x;
      o.y = acc[i][1] + bv.y;
      o.z = acc[i][2] + bv.z;
      o.w = acc[i][3] + bv.w;
      if (RELU) {
        o.x = fmaxf(o.x, 0.f); o.y = fmaxf(o.y, 0.f);
        o.z = fmaxf(o.z, 0.f); o.w = fmaxf(o.w, 0.f);
      }
      ((float4*)Y)[(size_t)gr * 32 + tc] = o;
    }
  }
}

// ---------------- aggregation: wave per node, lane owns 2 columns ----------------
__global__ __launch_bounds__(256) void k_agg(const float* __restrict__ hW, const int* __restrict__ offs,
                                             const int* __restrict__ csr_src, const float* __restrict__ csr_w,
                                             const float* __restrict__ dinv, const float* __restrict__ bias,
                                             float* __restrict__ out) {
  const int wave = threadIdx.x >> 6;       // 0..3
  const int lane = threadIdx.x & 63;       // owns cols lane*2, lane*2+1
  const int v = blockIdx.x * 4 + wave;
  if (v >= N_NODES) return;

  const float2* hW2 = (const float2*)hW;
  const float d = dinv[v];
  float2 self = hW2[(size_t)v * 64 + lane];
  float ax = d * d * self.x;
  float ay = d * d * self.y;

  const int lo = offs[v], hi = offs[v + 1];
  for (int idx = lo; idx < hi; ++idx) {
    int s = csr_src[idx];       // uniform across wave -> broadcast load
    float w = csr_w[idx];
    float2 m = hW2[(size_t)s * 64 + lane];
    ax += w * m.x;
    ay += w * m.y;
  }
  float2 bv = ((const float2*)bias)[lane];
  float2 o;
  o.x = fmaxf(ax + bv.x, 0.f);
  o.y = fmaxf(ay + bv.y, 0.f);
  ((float2*)out)[(size_t)v * 64 + lane] = o;
}

// ---------------- mean pool: one block per graph, segmented column sum ----------------
__global__ __launch_bounds__(1024) void k_pool(const float* __restrict__ h, const int* __restrict__ gstart,
                                               const int* __restrict__ gend, float* __restrict__ pooled) {
  __shared__ float red[1024];
  const int g = blockIdx.x;
  const int tid = threadIdx.x;
  const int j = tid & 127;      // column
  const int r0 = tid >> 7;      // 0..7 row phase
  const int lo = gstart[g], hi = gend[g];
  float acc = 0.f;
  for (int v = lo + r0; v < hi; v += 8) acc += h[(size_t)v * HID + j];
  red[tid] = acc;
  __syncthreads();
  if (r0 < 4) red[tid] += red[tid + 512];
  __syncthreads();
  if (r0 < 2) red[tid] += red[tid + 256];
  __syncthreads();
  if (r0 < 1) {
    float s = red[tid] + red[tid + 128];
    float c = fmaxf((float)(hi - lo), 1.f);
    pooled[g * HID + j] = s / c;
  }
}

// ---------------- heads: out[t,g,:] = pooled[g] @ W_t + b_t ----------------
__global__ __launch_bounds__(128) void k_heads(const float* __restrict__ pooled,
                                               const float* __restrict__ W0, const float* __restrict__ b0,
                                               const float* __restrict__ W1, const float* __restrict__ b1,
                                               const float* __restrict__ W2, const float* __restrict__ b2,
                                               float* __restrict__ out) {
  __shared__ float pm[HID];
  const int g = blockIdx.x, t = blockIdx.y, j = threadIdx.x;
  pm[j] = pooled[g * HID + j];
  __syncthreads();
  const float* W = (t == 0) ? W0 : ((t == 1) ? W1 : W2);
  const float* b = (t == 0) ? b0 : ((t == 1) ? b1 : b2);
  float acc = 0.f;
#pragma unroll 8
  for (int k = 0; k < HID; ++k) acc += pm[k] * W[k * HID + j];
  out[((size_t)t * NGRAPH + g) * HID + j] = acc + b[j];
}

extern "C" void kernel_launch(void* const* d_in, const int* in_sizes, int n_in,
                              void* d_out, int out_size, void* d_ws, size_t ws_size,
                              hipStream_t stream) {
  const float* x     = (const float*)d_in[0];
  const int*   ei    = (const int*)d_in[1];
  const int*   batch = (const int*)d_in[2];
  const float* W_in  = (const float*)d_in[3];
  const float* b_in  = (const float*)d_in[4];
  const float* convW = (const float*)d_in[5];
  const float* convb = (const float*)d_in[6];
  const float* W_def = (const float*)d_in[7];
  const float* b_def = (const float*)d_in[8];
  const float* W_syn = (const float*)d_in[9];
  const float* b_syn = (const float*)d_in[10];
  const float* W_rel = (const float*)d_in[11];
  const float* b_rel = (const float*)d_in[12];

  const int E = in_sizes[1] / 2;  // 640000
  const int* row = ei;            // source
  const int* col = ei + E;        // target (aggregation index)

  char* base = (char*)d_ws;
  size_t off = 0;
  auto alloc = [&](size_t bytes) -> void* {
    void* p = base + off;
    off += (bytes + 255) & ~size_t(255);
    return p;
  };
  int*   cnt     = (int*)  alloc((size_t)N_NODES * 4);
  float* dinv    = (float*)alloc((size_t)N_NODES * 4);
  int*   offs    = (int*)  alloc((size_t)(N_NODES + 1) * 4);
  int*   cursor  = (int*)  alloc((size_t)N_NODES * 4);
  int*   csr_src = (int*)  alloc((size_t)E * 4);
  float* csr_w   = (float*)alloc((size_t)E * 4);
  float* hA      = (float*)alloc((size_t)N_NODES * HID * 4);
  float* hB      = (float*)alloc((size_t)N_NODES * HID * 4);
  float* pooled  = (float*)alloc((size_t)NGRAPH * HID * 4);
  int*   gstart  = (int*)  alloc((size_t)NGRAPH * 4);
  int*   gend    = (int*)  alloc((size_t)NGRAPH * 4);

  // graph preprocessing
  k_init<<<(N_NODES + 255) / 256, 256, 0, stream>>>(cnt, gstart, gend);
  k_hist<<<(E + 255) / 256, 256, 0, stream>>>(col, E, cnt);
  k_bounds<<<(N_NODES + 255) / 256, 256, 0, stream>>>(batch, gstart, gend);
  k_scan<<<1, 512, 0, stream>>>(cnt, offs, cursor, dinv);
  k_fill<<<(E + 255) / 256, 256, 0, stream>>>(row, col, E, dinv, cursor, csr_src, csr_w);

  const int gemm_grid = (N_NODES + 63) / 64;
  k_gemm<true, true><<<gemm_grid, 256, 0, stream>>>(x, W_in, b_in, hA, N_NODES);

  for (int i = 0; i < NLAYERS; ++i) {
    k_gemm<false, false><<<gemm_grid, 256, 0, stream>>>(hA, convW + (size_t)i * HID * HID, nullptr, hB, N_NODES);
    k_agg<<<(N_NODES + 3) / 4, 256, 0, stream>>>(hB, offs, csr_src, csr_w, dinv, convb + (size_t)i * HID, hA);
  }

  k_pool<<<NGRAPH, 1024, 0, stream>>>(hA, gstart, gend, pooled);
  k_heads<<<dim3(NGRAPH, 3), HID, 0, stream>>>(pooled, W_def, b_def, W_syn, b_syn, W_rel, b_rel,
                                               (float*)d_out);
}

// Round 3
// 680.107 us; speedup vs baseline: 1.6238x; 1.4662x over previous
//
#include <hip/hip_runtime.h>
#include <hip/hip_bf16.h>

#define N_NODES 50000
#define NGRAPH 64
#define HID 128
#define NLAYERS 4

// ---------------- init: zero histogram + graph bounds ----------------
__global__ void k_init(int* __restrict__ cnt, int* __restrict__ gstart, int* __restrict__ gend) {
  int i = blockIdx.x * blockDim.x + threadIdx.x;
  if (i < N_NODES) cnt[i] = 0;
  if (i < NGRAPH) { gstart[i] = N_NODES; gend[i] = 0; }
}

// ---------------- in-degree histogram over target (col) ----------------
__global__ void k_hist(const int* __restrict__ col, int E, int* __restrict__ cnt) {
  int e = blockIdx.x * blockDim.x + threadIdx.x;
  if (e < E) atomicAdd(&cnt[col[e]], 1);
}

// ---------------- graph boundaries (batch sorted -> local boundary detect, no atomics) ----------------
__global__ void k_bounds(const int* __restrict__ batch, int* __restrict__ gstart, int* __restrict__ gend) {
  int i = blockIdx.x * blockDim.x + threadIdx.x;
  if (i >= N_NODES) return;
  int b = batch[i];
  if (i == 0 || batch[i - 1] != b) gstart[b] = i;
  if (i == N_NODES - 1 || batch[i + 1] != b) gend[b] = i + 1;
}

// ---------------- single-block exclusive scan -> offsets, cursor, dinv ----------------
__global__ __launch_bounds__(512) void k_scan(const int* __restrict__ cnt, int* __restrict__ offs,
                                              int* __restrict__ cursor, float* __restrict__ dinv) {
  __shared__ int part[512];
  const int t = threadIdx.x;
  const int CH = (N_NODES + 511) / 512;  // 98
  const int lo = t * CH;
  const int hi = min(lo + CH, N_NODES);
  int s = 0;
  for (int i = lo; i < hi; ++i) s += cnt[i];
  part[t] = s;
  __syncthreads();
  for (int off = 1; off < 512; off <<= 1) {
    int v = (t >= off) ? part[t - off] : 0;
    __syncthreads();
    part[t] += v;
    __syncthreads();
  }
  int base = (t == 0) ? 0 : part[t - 1];
  for (int i = lo; i < hi; ++i) {
    int c = cnt[i];
    offs[i] = base;
    cursor[i] = base;
    base += c;
    dinv[i] = 1.0f / sqrtf((float)(c + 1));  // self-loop included in degree
  }
  if (t == 511) offs[N_NODES] = part[511];
}

// ---------------- scatter edges into CSR buckets (by target) ----------------
__global__ void k_fill(const int* __restrict__ row, const int* __restrict__ col, int E,
                       const float* __restrict__ dinv, int* __restrict__ cursor,
                       int* __restrict__ csr_src, float* __restrict__ csr_w) {
  int e = blockIdx.x * blockDim.x + threadIdx.x;
  if (e >= E) return;
  int r = row[e], c = col[e];
  int pos = atomicAdd(&cursor[c], 1);
  csr_src[pos] = r;
  csr_w[pos] = dinv[r] * dinv[c];
}

// ---------------- f32 GEMM: Y[M,128] = X[M,128] @ W[128,128] (+bias)(+relu), optional bf16 out ----------------
template <bool BIAS, bool RELU, bool OUTBF16>
__global__ __launch_bounds__(256) void k_gemm(const float* __restrict__ X, const float* __restrict__ W,
                                              const float* __restrict__ bias, void* __restrict__ Yv, int M) {
  __shared__ float xs[64 * HID];  // 32 KB
  float4* xs4 = (float4*)xs;
  const float4* X4 = (const float4*)X;
  const float4* W4 = (const float4*)W;
  const int tid = threadIdx.x;
  const int rbase = blockIdx.x * 64;

#pragma unroll
  for (int t = 0; t < 8; ++t) {
    int idx = t * 256 + tid;
    int r = idx >> 5, c4 = idx & 31;
    int gr = rbase + r;
    float4 v = make_float4(0.f, 0.f, 0.f, 0.f);
    if (gr < M) v = X4[(size_t)gr * 32 + c4];
    xs4[idx] = v;
  }
  __syncthreads();

  const int tc = tid & 31;
  const int tr = tid >> 5;
  const int r0 = tr * 8;

  float acc[8][4];
#pragma unroll
  for (int i = 0; i < 8; ++i)
#pragma unroll
    for (int c = 0; c < 4; ++c) acc[i][c] = 0.f;

  for (int k4 = 0; k4 < 32; ++k4) {
    float4 w0 = W4[(k4 * 4 + 0) * 32 + tc];
    float4 w1 = W4[(k4 * 4 + 1) * 32 + tc];
    float4 w2 = W4[(k4 * 4 + 2) * 32 + tc];
    float4 w3 = W4[(k4 * 4 + 3) * 32 + tc];
#pragma unroll
    for (int i = 0; i < 8; ++i) {
      float4 xv = xs4[(r0 + i) * 32 + k4];
      acc[i][0] += xv.x * w0.x + xv.y * w1.x + xv.z * w2.x + xv.w * w3.x;
      acc[i][1] += xv.x * w0.y + xv.y * w1.y + xv.z * w2.y + xv.w * w3.y;
      acc[i][2] += xv.x * w0.z + xv.y * w1.z + xv.z * w2.z + xv.w * w3.z;
      acc[i][3] += xv.x * w0.w + xv.y * w1.w + xv.z * w2.w + xv.w * w3.w;
    }
  }

  float4 bv = make_float4(0.f, 0.f, 0.f, 0.f);
  if (BIAS) bv = ((const float4*)bias)[tc];
#pragma unroll
  for (int i = 0; i < 8; ++i) {
    int gr = rbase + r0 + i;
    if (gr < M) {
      float4 o;
      o.x = acc[i][0] + bv.x;
      o.y = acc[i][1] + bv.y;
      o.z = acc[i][2] + bv.z;
      o.w = acc[i][3] + bv.w;
      if (RELU) {
        o.x = fmaxf(o.x, 0.f); o.y = fmaxf(o.y, 0.f);
        o.z = fmaxf(o.z, 0.f); o.w = fmaxf(o.w, 0.f);
      }
      if (OUTBF16) {
        ushort4 p;
        p.x = __hip_bfloat16_raw(__float2bfloat16(o.x)).x;
        p.y = __hip_bfloat16_raw(__float2bfloat16(o.y)).x;
        p.z = __hip_bfloat16_raw(__float2bfloat16(o.z)).x;
        p.w = __hip_bfloat16_raw(__float2bfloat16(o.w)).x;
        ((ushort4*)Yv)[(size_t)gr * 32 + tc] = p;
      } else {
        ((float4*)Yv)[(size_t)gr * 32 + tc] = o;
      }
    }
  }
}

// ---------------- aggregation: wave per node, lane owns 2 cols; bf16 gather, f32 accumulate ----------------
__global__ __launch_bounds__(256) void k_agg(const __hip_bfloat16* __restrict__ hW, const int* __restrict__ offs,
                                             const int* __restrict__ csr_src, const float* __restrict__ csr_w,
                                             const float* __restrict__ dinv, const float* __restrict__ bias,
                                             float* __restrict__ out) {
  const int wave = threadIdx.x >> 6;       // 0..3
  const int lane = threadIdx.x & 63;       // owns cols lane*2, lane*2+1
  const int v = blockIdx.x * 4 + wave;
  if (v >= N_NODES) return;

  const uint* hW2 = (const uint*)hW;       // 2 bf16 per uint
  const float d = dinv[v];
  uint sv = hW2[(size_t)v * 64 + lane];
  float ax = d * d * __uint_as_float(sv << 16);
  float ay = d * d * __uint_as_float(sv & 0xffff0000u);

  const int lo = offs[v], hi = offs[v + 1];
  for (int idx = lo; idx < hi; ++idx) {
    int s = csr_src[idx];
    float w = csr_w[idx];
    uint m = hW2[(size_t)s * 64 + lane];
    ax += w * __uint_as_float(m << 16);
    ay += w * __uint_as_float(m & 0xffff0000u);
  }
  float2 bv = ((const float2*)bias)[lane];
  float2 o;
  o.x = fmaxf(ax + bv.x, 0.f);
  o.y = fmaxf(ay + bv.y, 0.f);
  ((float2*)out)[(size_t)v * 64 + lane] = o;
}

// ---------------- mean pool: one block per graph, segmented column sum ----------------
__global__ __launch_bounds__(1024) void k_pool(const float* __restrict__ h, const int* __restrict__ gstart,
                                               const int* __restrict__ gend, float* __restrict__ pooled) {
  __shared__ float red[1024];
  const int g = blockIdx.x;
  const int tid = threadIdx.x;
  const int j = tid & 127;      // column
  const int r0 = tid >> 7;      // 0..7 row phase
  const int lo = gstart[g], hi = gend[g];
  float acc = 0.f;
  for (int v = lo + r0; v < hi; v += 8) acc += h[(size_t)v * HID + j];
  red[tid] = acc;
  __syncthreads();
  if (r0 < 4) red[tid] += red[tid + 512];
  __syncthreads();
  if (r0 < 2) red[tid] += red[tid + 256];
  __syncthreads();
  if (r0 < 1) {
    float s = red[tid] + red[tid + 128];
    float c = fmaxf((float)(hi - lo), 1.f);
    pooled[g * HID + j] = s / c;
  }
}

// ---------------- heads: out[t,g,:] = pooled[g] @ W_t + b_t ----------------
__global__ __launch_bounds__(128) void k_heads(const float* __restrict__ pooled,
                                               const float* __restrict__ W0, const float* __restrict__ b0,
                                               const float* __restrict__ W1, const float* __restrict__ b1,
                                               const float* __restrict__ W2, const float* __restrict__ b2,
                                               float* __restrict__ out) {
  __shared__ float pm[HID];
  const int g = blockIdx.x, t = blockIdx.y, j = threadIdx.x;
  pm[j] = pooled[g * HID + j];
  __syncthreads();
  const float* W = (t == 0) ? W0 : ((t == 1) ? W1 : W2);
  const float* b = (t == 0) ? b0 : ((t == 1) ? b1 : b2);
  float acc = 0.f;
#pragma unroll 8
  for (int k = 0; k < HID; ++k) acc += pm[k] * W[k * HID + j];
  out[((size_t)t * NGRAPH + g) * HID + j] = acc + b[j];
}

extern "C" void kernel_launch(void* const* d_in, const int* in_sizes, int n_in,
                              void* d_out, int out_size, void* d_ws, size_t ws_size,
                              hipStream_t stream) {
  const float* x     = (const float*)d_in[0];
  const int*   ei    = (const int*)d_in[1];
  const int*   batch = (const int*)d_in[2];
  const float* W_in  = (const float*)d_in[3];
  const float* b_in  = (const float*)d_in[4];
  const float* convW = (const float*)d_in[5];
  const float* convb = (const float*)d_in[6];
  const float* W_def = (const float*)d_in[7];
  const float* b_def = (const float*)d_in[8];
  const float* W_syn = (const float*)d_in[9];
  const float* b_syn = (const float*)d_in[10];
  const float* W_rel = (const float*)d_in[11];
  const float* b_rel = (const float*)d_in[12];

  const int E = in_sizes[1] / 2;  // 640000
  const int* row = ei;            // source
  const int* col = ei + E;        // target (aggregation index)

  char* base = (char*)d_ws;
  size_t off = 0;
  auto alloc = [&](size_t bytes) -> void* {
    void* p = base + off;
    off += (bytes + 255) & ~size_t(255);
    return p;
  };
  int*   cnt     = (int*)  alloc((size_t)N_NODES * 4);
  float* dinv    = (float*)alloc((size_t)N_NODES * 4);
  int*   offs    = (int*)  alloc((size_t)(N_NODES + 1) * 4);
  int*   cursor  = (int*)  alloc((size_t)N_NODES * 4);
  int*   csr_src = (int*)  alloc((size_t)E * 4);
  float* csr_w   = (float*)alloc((size_t)E * 4);
  float* hA      = (float*)alloc((size_t)N_NODES * HID * 4);            // f32 h
  __hip_bfloat16* hB = (__hip_bfloat16*)alloc((size_t)N_NODES * HID * 2);  // bf16 hW
  float* pooled  = (float*)alloc((size_t)NGRAPH * HID * 4);
  int*   gstart  = (int*)  alloc((size_t)NGRAPH * 4);
  int*   gend    = (int*)  alloc((size_t)NGRAPH * 4);

  // graph preprocessing
  k_init<<<(N_NODES + 255) / 256, 256, 0, stream>>>(cnt, gstart, gend);
  k_hist<<<(E + 255) / 256, 256, 0, stream>>>(col, E, cnt);
  k_bounds<<<(N_NODES + 255) / 256, 256, 0, stream>>>(batch, gstart, gend);
  k_scan<<<1, 512, 0, stream>>>(cnt, offs, cursor, dinv);
  k_fill<<<(E + 255) / 256, 256, 0, stream>>>(row, col, E, dinv, cursor, csr_src, csr_w);

  const int gemm_grid = (N_NODES + 63) / 64;
  k_gemm<true, true, false><<<gemm_grid, 256, 0, stream>>>(x, W_in, b_in, hA, N_NODES);

  for (int i = 0; i < NLAYERS; ++i) {
    k_gemm<false, false, true><<<gemm_grid, 256, 0, stream>>>(hA, convW + (size_t)i * HID * HID, nullptr, hB, N_NODES);
    k_agg<<<(N_NODES + 3) / 4, 256, 0, stream>>>(hB, offs, csr_src, csr_w, dinv, convb + (size_t)i * HID, hA);
  }

  k_pool<<<NGRAPH, 1024, 0, stream>>>(hA, gstart, gend, pooled);
  k_heads<<<dim3(NGRAPH, 3), HID, 0, stream>>>(pooled, W_def, b_def, W_syn, b_syn, W_rel, b_rel,
                                               (float*)d_out);
}

// Round 4
// 542.335 us; speedup vs baseline: 2.0363x; 1.2540x over previous
//
#include <hip/hip_runtime.h>
#include <hip/hip_bf16.h>

#define N_NODES 50000
#define NGRAPH 64
#define HID 128
#define NLAYERS 4
#define SCAN_NB ((N_NODES + 511) / 512)   // 98 blocks

// ---------------- init: zero histogram + graph bounds ----------------
__global__ void k_init(int* __restrict__ cnt, int* __restrict__ gstart, int* __restrict__ gend) {
  int i = blockIdx.x * blockDim.x + threadIdx.x;
  if (i < N_NODES) cnt[i] = 0;
  if (i < NGRAPH) { gstart[i] = 0; gend[i] = 0; }
}

// ---------------- in-degree histogram over target (col) ----------------
__global__ void k_hist(const int* __restrict__ col, int E, int* __restrict__ cnt) {
  int e = blockIdx.x * blockDim.x + threadIdx.x;
  if (e < E) atomicAdd(&cnt[col[e]], 1);
}

// ---------------- graph boundaries (batch sorted -> local boundary detect, no atomics) ----------------
__global__ void k_bounds(const int* __restrict__ batch, int* __restrict__ gstart, int* __restrict__ gend) {
  int i = blockIdx.x * blockDim.x + threadIdx.x;
  if (i >= N_NODES) return;
  int b = batch[i];
  if (i == 0 || batch[i - 1] != b) gstart[b] = i;
  if (i == N_NODES - 1 || batch[i + 1] != b) gend[b] = i + 1;
}

// ---------------- multi-block scan, phase 1: block-local scan + block sums ----------------
__global__ __launch_bounds__(512) void k_scan1(const int* __restrict__ cnt, int* __restrict__ excl,
                                               int* __restrict__ bsum) {
  __shared__ int tmp[512];
  const int t = threadIdx.x;
  const int i = blockIdx.x * 512 + t;
  int v = (i < N_NODES) ? cnt[i] : 0;
  tmp[t] = v;
  __syncthreads();
#pragma unroll
  for (int off = 1; off < 512; off <<= 1) {
    int u = (t >= off) ? tmp[t - off] : 0;
    __syncthreads();
    tmp[t] += u;
    __syncthreads();
  }
  if (i < N_NODES) excl[i] = tmp[t] - v;
  if (t == 511) bsum[blockIdx.x] = tmp[511];
}

// ---------------- phase 2: single small block scans block sums -> exclusive bases ----------------
__global__ __launch_bounds__(128) void k_scan2(int* __restrict__ bsum, int* __restrict__ offs) {
  __shared__ int tmp[128];
  const int t = threadIdx.x;
  int v = (t < SCAN_NB) ? bsum[t] : 0;
  tmp[t] = v;
  __syncthreads();
#pragma unroll
  for (int off = 1; off < 128; off <<= 1) {
    int u = (t >= off) ? tmp[t - off] : 0;
    __syncthreads();
    tmp[t] += u;
    __syncthreads();
  }
  if (t < SCAN_NB) bsum[t] = tmp[t] - v;       // exclusive base per block
  if (t == 127) offs[N_NODES] = tmp[127];      // total edge count
}

// ---------------- phase 3: add base, emit offs/cursor/dinv ----------------
__global__ __launch_bounds__(512) void k_scan3(const int* __restrict__ cnt, const int* __restrict__ excl,
                                               const int* __restrict__ bsum, int* __restrict__ offs,
                                               int* __restrict__ cursor, float* __restrict__ dinv) {
  const int i = blockIdx.x * 512 + threadIdx.x;
  if (i >= N_NODES) return;
  int o = excl[i] + bsum[blockIdx.x];
  offs[i] = o;
  cursor[i] = o;
  dinv[i] = 1.0f / sqrtf((float)(cnt[i] + 1));  // self-loop included in degree
}

// ---------------- scatter edges into CSR buckets (by target) ----------------
__global__ void k_fill(const int* __restrict__ row, const int* __restrict__ col, int E,
                       const float* __restrict__ dinv, int* __restrict__ cursor,
                       int* __restrict__ csr_src, float* __restrict__ csr_w) {
  int e = blockIdx.x * blockDim.x + threadIdx.x;
  if (e >= E) return;
  int r = row[e], c = col[e];
  int pos = atomicAdd(&cursor[c], 1);
  csr_src[pos] = r;
  csr_w[pos] = dinv[r] * dinv[c];
}

// ---------------- f32 GEMM: Y[M,128] = X[M,128] @ W[128,128] (+bias)(+relu), optional bf16 out ----------------
template <bool BIAS, bool RELU, bool OUTBF16>
__global__ __launch_bounds__(256) void k_gemm(const float* __restrict__ X, const float* __restrict__ W,
                                              const float* __restrict__ bias, void* __restrict__ Yv, int M) {
  __shared__ float xs[64 * HID];  // 32 KB
  float4* xs4 = (float4*)xs;
  const float4* X4 = (const float4*)X;
  const float4* W4 = (const float4*)W;
  const int tid = threadIdx.x;
  const int rbase = blockIdx.x * 64;

#pragma unroll
  for (int t = 0; t < 8; ++t) {
    int idx = t * 256 + tid;
    int r = idx >> 5, c4 = idx & 31;
    int gr = rbase + r;
    float4 v = make_float4(0.f, 0.f, 0.f, 0.f);
    if (gr < M) v = X4[(size_t)gr * 32 + c4];
    xs4[idx] = v;
  }
  __syncthreads();

  const int tc = tid & 31;
  const int tr = tid >> 5;
  const int r0 = tr * 8;

  float acc[8][4];
#pragma unroll
  for (int i = 0; i < 8; ++i)
#pragma unroll
    for (int c = 0; c < 4; ++c) acc[i][c] = 0.f;

  for (int k4 = 0; k4 < 32; ++k4) {
    float4 w0 = W4[(k4 * 4 + 0) * 32 + tc];
    float4 w1 = W4[(k4 * 4 + 1) * 32 + tc];
    float4 w2 = W4[(k4 * 4 + 2) * 32 + tc];
    float4 w3 = W4[(k4 * 4 + 3) * 32 + tc];
#pragma unroll
    for (int i = 0; i < 8; ++i) {
      float4 xv = xs4[(r0 + i) * 32 + k4];
      acc[i][0] += xv.x * w0.x + xv.y * w1.x + xv.z * w2.x + xv.w * w3.x;
      acc[i][1] += xv.x * w0.y + xv.y * w1.y + xv.z * w2.y + xv.w * w3.y;
      acc[i][2] += xv.x * w0.z + xv.y * w1.z + xv.z * w2.z + xv.w * w3.z;
      acc[i][3] += xv.x * w0.w + xv.y * w1.w + xv.z * w2.w + xv.w * w3.w;
    }
  }

  float4 bv = make_float4(0.f, 0.f, 0.f, 0.f);
  if (BIAS) bv = ((const float4*)bias)[tc];
#pragma unroll
  for (int i = 0; i < 8; ++i) {
    int gr = rbase + r0 + i;
    if (gr < M) {
      float4 o;
      o.x = acc[i][0] + bv.x;
      o.y = acc[i][1] + bv.y;
      o.z = acc[i][2] + bv.z;
      o.w = acc[i][3] + bv.w;
      if (RELU) {
        o.x = fmaxf(o.x, 0.f); o.y = fmaxf(o.y, 0.f);
        o.z = fmaxf(o.z, 0.f); o.w = fmaxf(o.w, 0.f);
      }
      if (OUTBF16) {
        ushort4 p;
        p.x = __hip_bfloat16_raw(__float2bfloat16(o.x)).x;
        p.y = __hip_bfloat16_raw(__float2bfloat16(o.y)).x;
        p.z = __hip_bfloat16_raw(__float2bfloat16(o.z)).x;
        p.w = __hip_bfloat16_raw(__float2bfloat16(o.w)).x;
        ((ushort4*)Yv)[(size_t)gr * 32 + tc] = p;
      } else {
        ((float4*)Yv)[(size_t)gr * 32 + tc] = o;
      }
    }
  }
}

// ---------------- aggregation: wave per node, lane owns 2 cols; bf16 gather, f32 accumulate ----------------
__global__ __launch_bounds__(256) void k_agg(const __hip_bfloat16* __restrict__ hW, const int* __restrict__ offs,
                                             const int* __restrict__ csr_src, const float* __restrict__ csr_w,
                                             const float* __restrict__ dinv, const float* __restrict__ bias,
                                             float* __restrict__ out) {
  const int wave = threadIdx.x >> 6;       // 0..3
  const int lane = threadIdx.x & 63;       // owns cols lane*2, lane*2+1
  const int v = blockIdx.x * 4 + wave;
  if (v >= N_NODES) return;

  const uint* hW2 = (const uint*)hW;       // 2 bf16 per uint
  const float d = dinv[v];
  uint sv = hW2[(size_t)v * 64 + lane];
  float ax = d * d * __uint_as_float(sv << 16);
  float ay = d * d * __uint_as_float(sv & 0xffff0000u);

  const int lo = offs[v], hi = offs[v + 1];
  for (int idx = lo; idx < hi; ++idx) {
    int s = csr_src[idx];
    float w = csr_w[idx];
    uint m = hW2[(size_t)s * 64 + lane];
    ax += w * __uint_as_float(m << 16);
    ay += w * __uint_as_float(m & 0xffff0000u);
  }
  float2 bv = ((const float2*)bias)[lane];
  float2 o;
  o.x = fmaxf(ax + bv.x, 0.f);
  o.y = fmaxf(ay + bv.y, 0.f);
  ((float2*)out)[(size_t)v * 64 + lane] = o;
}

// ---------------- mean pool: one block per graph, segmented column sum ----------------
__global__ __launch_bounds__(1024) void k_pool(const float* __restrict__ h, const int* __restrict__ gstart,
                                               const int* __restrict__ gend, float* __restrict__ pooled) {
  __shared__ float red[1024];
  const int g = blockIdx.x;
  const int tid = threadIdx.x;
  const int j = tid & 127;      // column
  const int r0 = tid >> 7;      // 0..7 row phase
  const int lo = gstart[g], hi = gend[g];
  float acc = 0.f;
  for (int v = lo + r0; v < hi; v += 8) acc += h[(size_t)v * HID + j];
  red[tid] = acc;
  __syncthreads();
  if (r0 < 4) red[tid] += red[tid + 512];
  __syncthreads();
  if (r0 < 2) red[tid] += red[tid + 256];
  __syncthreads();
  if (r0 < 1) {
    float s = red[tid] + red[tid + 128];
    float c = fmaxf((float)(hi - lo), 1.f);
    pooled[g * HID + j] = s / c;
  }
}

// ---------------- heads: out[t,g,:] = pooled[g] @ W_t + b_t ----------------
__global__ __launch_bounds__(128) void k_heads(const float* __restrict__ pooled,
                                               const float* __restrict__ W0, const float* __restrict__ b0,
                                               const float* __restrict__ W1, const float* __restrict__ b1,
                                               const float* __restrict__ W2, const float* __restrict__ b2,
                                               float* __restrict__ out) {
  __shared__ float pm[HID];
  const int g = blockIdx.x, t = blockIdx.y, j = threadIdx.x;
  pm[j] = pooled[g * HID + j];
  __syncthreads();
  const float* W = (t == 0) ? W0 : ((t == 1) ? W1 : W2);
  const float* b = (t == 0) ? b0 : ((t == 1) ? b1 : b2);
  float acc = 0.f;
#pragma unroll 8
  for (int k = 0; k < HID; ++k) acc += pm[k] * W[k * HID + j];
  out[((size_t)t * NGRAPH + g) * HID + j] = acc + b[j];
}

extern "C" void kernel_launch(void* const* d_in, const int* in_sizes, int n_in,
                              void* d_out, int out_size, void* d_ws, size_t ws_size,
                              hipStream_t stream) {
  const float* x     = (const float*)d_in[0];
  const int*   ei    = (const int*)d_in[1];
  const int*   batch = (const int*)d_in[2];
  const float* W_in  = (const float*)d_in[3];
  const float* b_in  = (const float*)d_in[4];
  const float* convW = (const float*)d_in[5];
  const float* convb = (const float*)d_in[6];
  const float* W_def = (const float*)d_in[7];
  const float* b_def = (const float*)d_in[8];
  const float* W_syn = (const float*)d_in[9];
  const float* b_syn = (const float*)d_in[10];
  const float* W_rel = (const float*)d_in[11];
  const float* b_rel = (const float*)d_in[12];

  const int E = in_sizes[1] / 2;  // 640000
  const int* row = ei;            // source
  const int* col = ei + E;        // target (aggregation index)

  char* base = (char*)d_ws;
  size_t off = 0;
  auto alloc = [&](size_t bytes) -> void* {
    void* p = base + off;
    off += (bytes + 255) & ~size_t(255);
    return p;
  };
  int*   cnt     = (int*)  alloc((size_t)N_NODES * 4);
  float* dinv    = (float*)alloc((size_t)N_NODES * 4);
  int*   offs    = (int*)  alloc((size_t)(N_NODES + 1) * 4);
  int*   cursor  = (int*)  alloc((size_t)N_NODES * 4);
  int*   excl    = (int*)  alloc((size_t)N_NODES * 4);
  int*   bsum    = (int*)  alloc((size_t)SCAN_NB * 4);
  int*   csr_src = (int*)  alloc((size_t)E * 4);
  float* csr_w   = (float*)alloc((size_t)E * 4);
  float* hA      = (float*)alloc((size_t)N_NODES * HID * 4);               // f32 h
  __hip_bfloat16* hB = (__hip_bfloat16*)alloc((size_t)N_NODES * HID * 2);  // bf16 hW
  float* pooled  = (float*)alloc((size_t)NGRAPH * HID * 4);
  int*   gstart  = (int*)  alloc((size_t)NGRAPH * 4);
  int*   gend    = (int*)  alloc((size_t)NGRAPH * 4);

  // graph preprocessing
  k_init<<<(N_NODES + 255) / 256, 256, 0, stream>>>(cnt, gstart, gend);
  k_hist<<<(E + 255) / 256, 256, 0, stream>>>(col, E, cnt);
  k_bounds<<<(N_NODES + 255) / 256, 256, 0, stream>>>(batch, gstart, gend);
  k_scan1<<<SCAN_NB, 512, 0, stream>>>(cnt, excl, bsum);
  k_scan2<<<1, 128, 0, stream>>>(bsum, offs);
  k_scan3<<<SCAN_NB, 512, 0, stream>>>(cnt, excl, bsum, offs, cursor, dinv);
  k_fill<<<(E + 255) / 256, 256, 0, stream>>>(row, col, E, dinv, cursor, csr_src, csr_w);

  const int gemm_grid = (N_NODES + 63) / 64;
  k_gemm<true, true, false><<<gemm_grid, 256, 0, stream>>>(x, W_in, b_in, hA, N_NODES);

  for (int i = 0; i < NLAYERS; ++i) {
    k_gemm<false, false, true><<<gemm_grid, 256, 0, stream>>>(hA, convW + (size_t)i * HID * HID, nullptr, hB, N_NODES);
    k_agg<<<(N_NODES + 3) / 4, 256, 0, stream>>>(hB, offs, csr_src, csr_w, dinv, convb + (size_t)i * HID, hA);
  }

  k_pool<<<NGRAPH, 1024, 0, stream>>>(hA, gstart, gend, pooled);
  k_heads<<<dim3(NGRAPH, 3), HID, 0, stream>>>(pooled, W_def, b_def, W_syn, b_syn, W_rel, b_rel,
                                               (float*)d_out);
}

// Round 5
// 408.365 us; speedup vs baseline: 2.7044x; 1.3281x over previous
//
#include <hip/hip_runtime.h>
#include <hip/hip_bf16.h>

#define N_NODES 50000
#define NGRAPH 64
#define HID 128
#define NLAYERS 4
#define SCAN_NB ((N_NODES + 511) / 512)   // 98 blocks

typedef __attribute__((ext_vector_type(8))) __bf16 bf16x8;
typedef __attribute__((ext_vector_type(8))) unsigned short ushort8;
typedef __attribute__((ext_vector_type(4))) float f32x4;

__device__ __forceinline__ float bf2f(unsigned short u) { return __uint_as_float(((unsigned)u) << 16); }
__device__ __forceinline__ unsigned short f2bf(float f) { return __hip_bfloat16_raw(__float2bfloat16(f)).x; }

// ---------------- init: zero histogram + graph bounds ----------------
__global__ void k_init(int* __restrict__ cnt, int* __restrict__ gstart, int* __restrict__ gend) {
  int i = blockIdx.x * blockDim.x + threadIdx.x;
  if (i < N_NODES) cnt[i] = 0;
  if (i < NGRAPH) { gstart[i] = 0; gend[i] = 0; }
}

// ---------------- in-degree histogram over target (col) ----------------
__global__ void k_hist(const int* __restrict__ col, int E, int* __restrict__ cnt) {
  int e = blockIdx.x * blockDim.x + threadIdx.x;
  if (e < E) atomicAdd(&cnt[col[e]], 1);
}

// ---------------- graph boundaries (batch sorted -> local boundary detect) ----------------
__global__ void k_bounds(const int* __restrict__ batch, int* __restrict__ gstart, int* __restrict__ gend) {
  int i = blockIdx.x * blockDim.x + threadIdx.x;
  if (i >= N_NODES) return;
  int b = batch[i];
  if (i == 0 || batch[i - 1] != b) gstart[b] = i;
  if (i == N_NODES - 1 || batch[i + 1] != b) gend[b] = i + 1;
}

// ---------------- multi-block scan, phase 1 ----------------
__global__ __launch_bounds__(512) void k_scan1(const int* __restrict__ cnt, int* __restrict__ excl,
                                               int* __restrict__ bsum) {
  __shared__ int tmp[512];
  const int t = threadIdx.x;
  const int i = blockIdx.x * 512 + t;
  int v = (i < N_NODES) ? cnt[i] : 0;
  tmp[t] = v;
  __syncthreads();
#pragma unroll
  for (int off = 1; off < 512; off <<= 1) {
    int u = (t >= off) ? tmp[t - off] : 0;
    __syncthreads();
    tmp[t] += u;
    __syncthreads();
  }
  if (i < N_NODES) excl[i] = tmp[t] - v;
  if (t == 511) bsum[blockIdx.x] = tmp[511];
}

// ---------------- phase 2: scan block sums ----------------
__global__ __launch_bounds__(128) void k_scan2(int* __restrict__ bsum, int* __restrict__ offs) {
  __shared__ int tmp[128];
  const int t = threadIdx.x;
  int v = (t < SCAN_NB) ? bsum[t] : 0;
  tmp[t] = v;
  __syncthreads();
#pragma unroll
  for (int off = 1; off < 128; off <<= 1) {
    int u = (t >= off) ? tmp[t - off] : 0;
    __syncthreads();
    tmp[t] += u;
    __syncthreads();
  }
  if (t < SCAN_NB) bsum[t] = tmp[t] - v;
  if (t == 127) offs[N_NODES] = tmp[127];
}

// ---------------- phase 3: emit offs/cursor/dinv ----------------
__global__ __launch_bounds__(512) void k_scan3(const int* __restrict__ cnt, const int* __restrict__ excl,
                                               const int* __restrict__ bsum, int* __restrict__ offs,
                                               int* __restrict__ cursor, float* __restrict__ dinv) {
  const int i = blockIdx.x * 512 + threadIdx.x;
  if (i >= N_NODES) return;
  int o = excl[i] + bsum[blockIdx.x];
  offs[i] = o;
  cursor[i] = o;
  dinv[i] = 1.0f / sqrtf((float)(cnt[i] + 1));
}

// ---------------- scatter edges into CSR buckets (by target) ----------------
__global__ void k_fill(const int* __restrict__ row, const int* __restrict__ col, int E,
                       const float* __restrict__ dinv, int* __restrict__ cursor,
                       int* __restrict__ csr_src, float* __restrict__ csr_w) {
  int e = blockIdx.x * blockDim.x + threadIdx.x;
  if (e >= E) return;
  int r = row[e], c = col[e];
  int pos = atomicAdd(&cursor[c], 1);
  csr_src[pos] = r;
  csr_w[pos] = dinv[r] * dinv[c];
}

// ---------------- weight prep: f32 W[k][n] -> bf16 W^T[n][k], 5 matrices ----------------
__global__ void k_wprep(const float* __restrict__ Win, const float* __restrict__ Wconv,
                        unsigned short* __restrict__ WtAll) {
  int idx = blockIdx.x * 256 + threadIdx.x;
  if (idx >= 5 * HID * HID) return;
  int m = idx >> 14, rem = idx & 16383;
  int k = rem >> 7, n = rem & 127;
  const float* src = (m == 0) ? Win : (Wconv + (size_t)(m - 1) * HID * HID);
  WtAll[(size_t)m * HID * HID + n * HID + k] = f2bf(src[k * HID + n]);
}

// ---------------- MFMA GEMM: Y[M,128] = A[M,128] @ W, W^T given bf16 [n][k] ----------------
// wave = 16 output rows; 4 waves/block = 64 rows; LDS-free.
// A-frag and B-frag use the same lane->k mapping => result correct by permutation invariance.
template <bool AF32, bool BIAS, bool RELU>
__global__ __launch_bounds__(256) void k_gemm_mfma(const void* __restrict__ Av,
                                                   const unsigned short* __restrict__ Wt,
                                                   const float* __restrict__ bias,
                                                   unsigned short* __restrict__ Y, int M) {
  const int wave = threadIdx.x >> 6;
  const int lane = threadIdx.x & 63;
  const int row16 = (blockIdx.x * 4 + wave) * 16;
  if (row16 >= M) return;                 // M % 16 == 0, so full tiles only
  const int lr = lane & 15;               // A row within tile / B col within tile
  const int lk = (lane >> 4) * 8;         // k sub-offset

  f32x4 acc[8];
#pragma unroll
  for (int i = 0; i < 8; ++i) acc[i] = (f32x4){0.f, 0.f, 0.f, 0.f};

  const int arow = row16 + lr;
#pragma unroll
  for (int ks = 0; ks < 4; ++ks) {
    const int k0 = ks * 32 + lk;
    bf16x8 a;
    if (AF32) {
      const float* Af = (const float*)Av;
      float4 f0 = *(const float4*)(Af + (size_t)arow * HID + k0);
      float4 f1 = *(const float4*)(Af + (size_t)arow * HID + k0 + 4);
      ushort8 u;
      u[0] = f2bf(f0.x); u[1] = f2bf(f0.y); u[2] = f2bf(f0.z); u[3] = f2bf(f0.w);
      u[4] = f2bf(f1.x); u[5] = f2bf(f1.y); u[6] = f2bf(f1.z); u[7] = f2bf(f1.w);
      a = __builtin_bit_cast(bf16x8, u);
    } else {
      const unsigned short* Ab = (const unsigned short*)Av;
      a = *(const bf16x8*)(Ab + (size_t)arow * HID + k0);
    }
#pragma unroll
    for (int nt = 0; nt < 8; ++nt) {
      bf16x8 b = *(const bf16x8*)(Wt + (size_t)(nt * 16 + lr) * HID + k0);
      acc[nt] = __builtin_amdgcn_mfma_f32_16x16x32_bf16(a, b, acc[nt], 0, 0, 0);
    }
  }

  // D layout: col = lane&15, row = (lane>>4)*4 + r   [verified m89]
  const int drow = row16 + (lane >> 4) * 4;
#pragma unroll
  for (int nt = 0; nt < 8; ++nt) {
    const int gcol = nt * 16 + lr;
    float bv = BIAS ? bias[gcol] : 0.f;
#pragma unroll
    for (int r = 0; r < 4; ++r) {
      float v = acc[nt][r] + bv;
      if (RELU) v = fmaxf(v, 0.f);
      Y[(size_t)(drow + r) * HID + gcol] = f2bf(v);
    }
  }
}

// ---------------- aggregation: wave per node, 2x unrolled gather; bf16 in/out, f32 accum ----------------
__global__ __launch_bounds__(256) void k_agg(const unsigned short* __restrict__ hW, const int* __restrict__ offs,
                                             const int* __restrict__ csr_src, const float* __restrict__ csr_w,
                                             const float* __restrict__ dinv, const float* __restrict__ bias,
                                             unsigned short* __restrict__ out) {
  const int wave = threadIdx.x >> 6;
  const int lane = threadIdx.x & 63;       // owns cols lane*2, lane*2+1
  const int v = blockIdx.x * 4 + wave;
  if (v >= N_NODES) return;

  const unsigned* hW2 = (const unsigned*)hW;   // 2 bf16 per uint
  const float d = dinv[v];
  unsigned sv = hW2[(size_t)v * 64 + lane];
  float ax = d * d * __uint_as_float(sv << 16);
  float ay = d * d * __uint_as_float(sv & 0xffff0000u);

  const int lo = offs[v], hi = offs[v + 1];
  int idx = lo;
  for (; idx + 2 <= hi; idx += 2) {
    int s0 = csr_src[idx];
    int s1 = csr_src[idx + 1];
    float w0 = csr_w[idx];
    float w1 = csr_w[idx + 1];
    unsigned m0 = hW2[(size_t)s0 * 64 + lane];
    unsigned m1 = hW2[(size_t)s1 * 64 + lane];
    ax += w0 * __uint_as_float(m0 << 16);
    ay += w0 * __uint_as_float(m0 & 0xffff0000u);
    ax += w1 * __uint_as_float(m1 << 16);
    ay += w1 * __uint_as_float(m1 & 0xffff0000u);
  }
  if (idx < hi) {
    int s0 = csr_src[idx];
    float w0 = csr_w[idx];
    unsigned m0 = hW2[(size_t)s0 * 64 + lane];
    ax += w0 * __uint_as_float(m0 << 16);
    ay += w0 * __uint_as_float(m0 & 0xffff0000u);
  }
  float2 bv = ((const float2*)bias)[lane];
  float ox = fmaxf(ax + bv.x, 0.f);
  float oy = fmaxf(ay + bv.y, 0.f);
  unsigned packed = (unsigned)f2bf(ox) | ((unsigned)f2bf(oy) << 16);
  ((unsigned*)out)[(size_t)v * 64 + lane] = packed;
}

// ---------------- mean pool: one block per graph, bf16 in, f32 accum ----------------
__global__ __launch_bounds__(1024) void k_pool(const unsigned short* __restrict__ h, const int* __restrict__ gstart,
                                               const int* __restrict__ gend, float* __restrict__ pooled) {
  __shared__ float red[1024];
  const int g = blockIdx.x;
  const int tid = threadIdx.x;
  const int j = tid & 127;
  const int r0 = tid >> 7;
  const int lo = gstart[g], hi = gend[g];
  float acc = 0.f;
  for (int v = lo + r0; v < hi; v += 8) acc += bf2f(h[(size_t)v * HID + j]);
  red[tid] = acc;
  __syncthreads();
  if (r0 < 4) red[tid] += red[tid + 512];
  __syncthreads();
  if (r0 < 2) red[tid] += red[tid + 256];
  __syncthreads();
  if (r0 < 1) {
    float s = red[tid] + red[tid + 128];
    float c = fmaxf((float)(hi - lo), 1.f);
    pooled[g * HID + j] = s / c;
  }
}

// ---------------- heads ----------------
__global__ __launch_bounds__(128) void k_heads(const float* __restrict__ pooled,
                                               const float* __restrict__ W0, const float* __restrict__ b0,
                                               const float* __restrict__ W1, const float* __restrict__ b1,
                                               const float* __restrict__ W2, const float* __restrict__ b2,
                                               float* __restrict__ out) {
  __shared__ float pm[HID];
  const int g = blockIdx.x, t = blockIdx.y, j = threadIdx.x;
  pm[j] = pooled[g * HID + j];
  __syncthreads();
  const float* W = (t == 0) ? W0 : ((t == 1) ? W1 : W2);
  const float* b = (t == 0) ? b0 : ((t == 1) ? b1 : b2);
  float acc = 0.f;
#pragma unroll 8
  for (int k = 0; k < HID; ++k) acc += pm[k] * W[k * HID + j];
  out[((size_t)t * NGRAPH + g) * HID + j] = acc + b[j];
}

extern "C" void kernel_launch(void* const* d_in, const int* in_sizes, int n_in,
                              void* d_out, int out_size, void* d_ws, size_t ws_size,
                              hipStream_t stream) {
  const float* x     = (const float*)d_in[0];
  const int*   ei    = (const int*)d_in[1];
  const int*   batch = (const int*)d_in[2];
  const float* W_in  = (const float*)d_in[3];
  const float* b_in  = (const float*)d_in[4];
  const float* convW = (const float*)d_in[5];
  const float* convb = (const float*)d_in[6];
  const float* W_def = (const float*)d_in[7];
  const float* b_def = (const float*)d_in[8];
  const float* W_syn = (const float*)d_in[9];
  const float* b_syn = (const float*)d_in[10];
  const float* W_rel = (const float*)d_in[11];
  const float* b_rel = (const float*)d_in[12];

  const int E = in_sizes[1] / 2;  // 640000
  const int* row = ei;            // source
  const int* col = ei + E;        // target

  char* base = (char*)d_ws;
  size_t off = 0;
  auto alloc = [&](size_t bytes) -> void* {
    void* p = base + off;
    off += (bytes + 255) & ~size_t(255);
    return p;
  };
  int*   cnt     = (int*)  alloc((size_t)N_NODES * 4);
  float* dinv    = (float*)alloc((size_t)N_NODES * 4);
  int*   offs    = (int*)  alloc((size_t)(N_NODES + 1) * 4);
  int*   cursor  = (int*)  alloc((size_t)N_NODES * 4);
  int*   excl    = (int*)  alloc((size_t)N_NODES * 4);
  int*   bsum    = (int*)  alloc((size_t)SCAN_NB * 4);
  int*   csr_src = (int*)  alloc((size_t)E * 4);
  float* csr_w   = (float*)alloc((size_t)E * 4);
  unsigned short* hA = (unsigned short*)alloc((size_t)N_NODES * HID * 2);  // bf16 h
  unsigned short* hB = (unsigned short*)alloc((size_t)N_NODES * HID * 2);  // bf16 hW
  unsigned short* WtAll = (unsigned short*)alloc((size_t)5 * HID * HID * 2); // bf16 W^T x5
  float* pooled  = (float*)alloc((size_t)NGRAPH * HID * 4);
  int*   gstart  = (int*)  alloc((size_t)NGRAPH * 4);
  int*   gend    = (int*)  alloc((size_t)NGRAPH * 4);

  // graph preprocessing
  k_init<<<(N_NODES + 255) / 256, 256, 0, stream>>>(cnt, gstart, gend);
  k_hist<<<(E + 255) / 256, 256, 0, stream>>>(col, E, cnt);
  k_bounds<<<(N_NODES + 255) / 256, 256, 0, stream>>>(batch, gstart, gend);
  k_scan1<<<SCAN_NB, 512, 0, stream>>>(cnt, excl, bsum);
  k_scan2<<<1, 128, 0, stream>>>(bsum, offs);
  k_scan3<<<SCAN_NB, 512, 0, stream>>>(cnt, excl, bsum, offs, cursor, dinv);
  k_fill<<<(E + 255) / 256, 256, 0, stream>>>(row, col, E, dinv, cursor, csr_src, csr_w);
  k_wprep<<<(5 * HID * HID + 255) / 256, 256, 0, stream>>>(W_in, convW, WtAll);

  const int gemm_grid = (N_NODES + 63) / 64;
  // h = relu(x @ W_in + b_in)  (x f32 -> bf16 in-register)
  k_gemm_mfma<true, true, true><<<gemm_grid, 256, 0, stream>>>(x, WtAll, b_in, hA, N_NODES);

  for (int i = 0; i < NLAYERS; ++i) {
    k_gemm_mfma<false, false, false><<<gemm_grid, 256, 0, stream>>>(
        hA, WtAll + (size_t)(i + 1) * HID * HID, nullptr, hB, N_NODES);
    k_agg<<<(N_NODES + 3) / 4, 256, 0, stream>>>(hB, offs, csr_src, csr_w, dinv, convb + (size_t)i * HID, hA);
  }

  k_pool<<<NGRAPH, 1024, 0, stream>>>(hA, gstart, gend, pooled);
  k_heads<<<dim3(NGRAPH, 3), HID, 0, stream>>>(pooled, W_def, b_def, W_syn, b_syn, W_rel, b_rel,
                                               (float*)d_out);
}

// Round 6
// 368.623 us; speedup vs baseline: 2.9960x; 1.1078x over previous
//
#include <hip/hip_runtime.h>
#include <hip/hip_bf16.h>

#define N_NODES 50000
#define NGRAPH 64
#define HID 128
#define NLAYERS 4
#define SCAN_NB ((N_NODES + 511) / 512)   // 98 blocks

typedef __attribute__((ext_vector_type(8))) __bf16 bf16x8;
typedef __attribute__((ext_vector_type(8))) unsigned short ushort8;
typedef __attribute__((ext_vector_type(4))) float f32x4;

__device__ __forceinline__ float bf2f(unsigned short u) { return __uint_as_float(((unsigned)u) << 16); }
__device__ __forceinline__ unsigned short f2bf(float f) { return __hip_bfloat16_raw(__float2bfloat16(f)).x; }

// ---------------- init: zero histogram + graph bounds ----------------
__global__ void k_init(int* __restrict__ cnt, int* __restrict__ gstart, int* __restrict__ gend) {
  int i = blockIdx.x * blockDim.x + threadIdx.x;
  if (i < N_NODES) cnt[i] = 0;
  if (i < NGRAPH) { gstart[i] = 0; gend[i] = 0; }
}

// ---------------- in-degree histogram over target (col) ----------------
__global__ void k_hist(const int* __restrict__ col, int E, int* __restrict__ cnt) {
  int e = blockIdx.x * blockDim.x + threadIdx.x;
  if (e < E) atomicAdd(&cnt[col[e]], 1);
}

// ---------------- graph boundaries (batch sorted -> local boundary detect) ----------------
__global__ void k_bounds(const int* __restrict__ batch, int* __restrict__ gstart, int* __restrict__ gend) {
  int i = blockIdx.x * blockDim.x + threadIdx.x;
  if (i >= N_NODES) return;
  int b = batch[i];
  if (i == 0 || batch[i - 1] != b) gstart[b] = i;
  if (i == N_NODES - 1 || batch[i + 1] != b) gend[b] = i + 1;
}

// ---------------- multi-block scan, phase 1 ----------------
__global__ __launch_bounds__(512) void k_scan1(const int* __restrict__ cnt, int* __restrict__ excl,
                                               int* __restrict__ bsum) {
  __shared__ int tmp[512];
  const int t = threadIdx.x;
  const int i = blockIdx.x * 512 + t;
  int v = (i < N_NODES) ? cnt[i] : 0;
  tmp[t] = v;
  __syncthreads();
#pragma unroll
  for (int off = 1; off < 512; off <<= 1) {
    int u = (t >= off) ? tmp[t - off] : 0;
    __syncthreads();
    tmp[t] += u;
    __syncthreads();
  }
  if (i < N_NODES) excl[i] = tmp[t] - v;
  if (t == 511) bsum[blockIdx.x] = tmp[511];
}

// ---------------- phase 2: scan block sums ----------------
__global__ __launch_bounds__(128) void k_scan2(int* __restrict__ bsum, int* __restrict__ offs) {
  __shared__ int tmp[128];
  const int t = threadIdx.x;
  int v = (t < SCAN_NB) ? bsum[t] : 0;
  tmp[t] = v;
  __syncthreads();
#pragma unroll
  for (int off = 1; off < 128; off <<= 1) {
    int u = (t >= off) ? tmp[t - off] : 0;
    __syncthreads();
    tmp[t] += u;
    __syncthreads();
  }
  if (t < SCAN_NB) bsum[t] = tmp[t] - v;
  if (t == 127) offs[N_NODES] = tmp[127];
}

// ---------------- phase 3: emit offs/cursor/dinv ----------------
__global__ __launch_bounds__(512) void k_scan3(const int* __restrict__ cnt, const int* __restrict__ excl,
                                               const int* __restrict__ bsum, int* __restrict__ offs,
                                               int* __restrict__ cursor, float* __restrict__ dinv) {
  const int i = blockIdx.x * 512 + threadIdx.x;
  if (i >= N_NODES) return;
  int o = excl[i] + bsum[blockIdx.x];
  offs[i] = o;
  cursor[i] = o;
  dinv[i] = 1.0f / sqrtf((float)(cnt[i] + 1));
}

// ---------------- scatter edges into CSR buckets (src only, 4B/edge) ----------------
__global__ void k_fill(const int* __restrict__ row, const int* __restrict__ col, int E,
                       int* __restrict__ cursor, int* __restrict__ csr_src) {
  int e = blockIdx.x * blockDim.x + threadIdx.x;
  if (e >= E) return;
  int pos = atomicAdd(&cursor[col[e]], 1);
  csr_src[pos] = row[e];
}

// ---------------- weight prep: f32 W[k][n] -> bf16 W^T[n][k], 5 matrices ----------------
__global__ void k_wprep(const float* __restrict__ Win, const float* __restrict__ Wconv,
                        unsigned short* __restrict__ WtAll) {
  int idx = blockIdx.x * 256 + threadIdx.x;
  if (idx >= 5 * HID * HID) return;
  int m = idx >> 14, rem = idx & 16383;
  int k = rem >> 7, n = rem & 127;
  const float* src = (m == 0) ? Win : (Wconv + (size_t)(m - 1) * HID * HID);
  WtAll[(size_t)m * HID * HID + n * HID + k] = f2bf(src[k * HID + n]);
}

// ---------------- MFMA GEMM: Y[M,128] = A[M,128] @ W, W^T given bf16 [n][k] ----------------
// wave = 16 output rows; 4 waves/block; LDS-free.
// SCALE: multiply output row r by dinv[r] (produces g = dinv*hW for the agg step).
template <bool AF32, bool BIAS, bool RELU, bool SCALE>
__global__ __launch_bounds__(256) void k_gemm_mfma(const void* __restrict__ Av,
                                                   const unsigned short* __restrict__ Wt,
                                                   const float* __restrict__ bias,
                                                   const float* __restrict__ dinv,
                                                   unsigned short* __restrict__ Y, int M) {
  const int wave = threadIdx.x >> 6;
  const int lane = threadIdx.x & 63;
  const int row16 = (blockIdx.x * 4 + wave) * 16;
  if (row16 >= M) return;
  const int lr = lane & 15;               // A row within tile / B col within tile
  const int lk = (lane >> 4) * 8;         // k sub-offset

  f32x4 acc[8];
#pragma unroll
  for (int i = 0; i < 8; ++i) acc[i] = (f32x4){0.f, 0.f, 0.f, 0.f};

  const int arow = row16 + lr;
#pragma unroll
  for (int ks = 0; ks < 4; ++ks) {
    const int k0 = ks * 32 + lk;
    bf16x8 a;
    if (AF32) {
      const float* Af = (const float*)Av;
      float4 f0 = *(const float4*)(Af + (size_t)arow * HID + k0);
      float4 f1 = *(const float4*)(Af + (size_t)arow * HID + k0 + 4);
      ushort8 u;
      u[0] = f2bf(f0.x); u[1] = f2bf(f0.y); u[2] = f2bf(f0.z); u[3] = f2bf(f0.w);
      u[4] = f2bf(f1.x); u[5] = f2bf(f1.y); u[6] = f2bf(f1.z); u[7] = f2bf(f1.w);
      a = __builtin_bit_cast(bf16x8, u);
    } else {
      const unsigned short* Ab = (const unsigned short*)Av;
      a = *(const bf16x8*)(Ab + (size_t)arow * HID + k0);
    }
#pragma unroll
    for (int nt = 0; nt < 8; ++nt) {
      bf16x8 b = *(const bf16x8*)(Wt + (size_t)(nt * 16 + lr) * HID + k0);
      acc[nt] = __builtin_amdgcn_mfma_f32_16x16x32_bf16(a, b, acc[nt], 0, 0, 0);
    }
  }

  // D layout: col = lane&15, row = (lane>>4)*4 + r
  const int drow = row16 + (lane >> 4) * 4;
  float4 dv = make_float4(1.f, 1.f, 1.f, 1.f);
  if (SCALE) dv = *(const float4*)(dinv + drow);
#pragma unroll
  for (int nt = 0; nt < 8; ++nt) {
    const int gcol = nt * 16 + lr;
    float bv = BIAS ? bias[gcol] : 0.f;
#pragma unroll
    for (int r = 0; r < 4; ++r) {
      float v = acc[nt][r] + bv;
      if (RELU) v = fmaxf(v, 0.f);
      if (SCALE) v *= ((const float*)&dv)[r];
      Y[(size_t)(drow + r) * HID + gcol] = f2bf(v);
    }
  }
}

// ---------------- aggregation: out[v] = relu(d * (g[v] + sum g[src]) + b); 4x unrolled gather ----------------
__global__ __launch_bounds__(256) void k_agg(const unsigned short* __restrict__ g, const int* __restrict__ offs,
                                             const int* __restrict__ csr_src, const float* __restrict__ dinv,
                                             const float* __restrict__ bias, unsigned short* __restrict__ out) {
  const int wave = threadIdx.x >> 6;
  const int lane = threadIdx.x & 63;       // owns cols lane*2, lane*2+1
  const int v = blockIdx.x * 4 + wave;
  if (v >= N_NODES) return;

  const unsigned* g2 = (const unsigned*)g;   // 2 bf16 per uint
  unsigned sv = g2[(size_t)v * 64 + lane];   // self term g[v]
  float ax = __uint_as_float(sv << 16);
  float ay = __uint_as_float(sv & 0xffff0000u);

  const int lo = offs[v], hi = offs[v + 1];
  int idx = lo;
  for (; idx + 4 <= hi; idx += 4) {
    int s0 = csr_src[idx];
    int s1 = csr_src[idx + 1];
    int s2 = csr_src[idx + 2];
    int s3 = csr_src[idx + 3];
    unsigned m0 = g2[(size_t)s0 * 64 + lane];
    unsigned m1 = g2[(size_t)s1 * 64 + lane];
    unsigned m2 = g2[(size_t)s2 * 64 + lane];
    unsigned m3 = g2[(size_t)s3 * 64 + lane];
    ax += __uint_as_float(m0 << 16);
    ay += __uint_as_float(m0 & 0xffff0000u);
    ax += __uint_as_float(m1 << 16);
    ay += __uint_as_float(m1 & 0xffff0000u);
    ax += __uint_as_float(m2 << 16);
    ay += __uint_as_float(m2 & 0xffff0000u);
    ax += __uint_as_float(m3 << 16);
    ay += __uint_as_float(m3 & 0xffff0000u);
  }
  for (; idx < hi; ++idx) {
    int s0 = csr_src[idx];
    unsigned m0 = g2[(size_t)s0 * 64 + lane];
    ax += __uint_as_float(m0 << 16);
    ay += __uint_as_float(m0 & 0xffff0000u);
  }
  const float d = dinv[v];
  float2 bv = ((const float2*)bias)[lane];
  float ox = fmaxf(d * ax + bv.x, 0.f);
  float oy = fmaxf(d * ay + bv.y, 0.f);
  unsigned packed = (unsigned)f2bf(ox) | ((unsigned)f2bf(oy) << 16);
  ((unsigned*)out)[(size_t)v * 64 + lane] = packed;
}

// ---------------- mean pool: one block per graph, bf16 in, f32 accum ----------------
__global__ __launch_bounds__(1024) void k_pool(const unsigned short* __restrict__ h, const int* __restrict__ gstart,
                                               const int* __restrict__ gend, float* __restrict__ pooled) {
  __shared__ float red[1024];
  const int g = blockIdx.x;
  const int tid = threadIdx.x;
  const int j = tid & 127;
  const int r0 = tid >> 7;
  const int lo = gstart[g], hi = gend[g];
  float acc = 0.f;
  for (int v = lo + r0; v < hi; v += 8) acc += bf2f(h[(size_t)v * HID + j]);
  red[tid] = acc;
  __syncthreads();
  if (r0 < 4) red[tid] += red[tid + 512];
  __syncthreads();
  if (r0 < 2) red[tid] += red[tid + 256];
  __syncthreads();
  if (r0 < 1) {
    float s = red[tid] + red[tid + 128];
    float c = fmaxf((float)(hi - lo), 1.f);
    pooled[g * HID + j] = s / c;
  }
}

// ---------------- heads ----------------
__global__ __launch_bounds__(128) void k_heads(const float* __restrict__ pooled,
                                               const float* __restrict__ W0, const float* __restrict__ b0,
                                               const float* __restrict__ W1, const float* __restrict__ b1,
                                               const float* __restrict__ W2, const float* __restrict__ b2,
                                               float* __restrict__ out) {
  __shared__ float pm[HID];
  const int g = blockIdx.x, t = blockIdx.y, j = threadIdx.x;
  pm[j] = pooled[g * HID + j];
  __syncthreads();
  const float* W = (t == 0) ? W0 : ((t == 1) ? W1 : W2);
  const float* b = (t == 0) ? b0 : ((t == 1) ? b1 : b2);
  float acc = 0.f;
#pragma unroll 8
  for (int k = 0; k < HID; ++k) acc += pm[k] * W[k * HID + j];
  out[((size_t)t * NGRAPH + g) * HID + j] = acc + b[j];
}

extern "C" void kernel_launch(void* const* d_in, const int* in_sizes, int n_in,
                              void* d_out, int out_size, void* d_ws, size_t ws_size,
                              hipStream_t stream) {
  const float* x     = (const float*)d_in[0];
  const int*   ei    = (const int*)d_in[1];
  const int*   batch = (const int*)d_in[2];
  const float* W_in  = (const float*)d_in[3];
  const float* b_in  = (const float*)d_in[4];
  const float* convW = (const float*)d_in[5];
  const float* convb = (const float*)d_in[6];
  const float* W_def = (const float*)d_in[7];
  const float* b_def = (const float*)d_in[8];
  const float* W_syn = (const float*)d_in[9];
  const float* b_syn = (const float*)d_in[10];
  const float* W_rel = (const float*)d_in[11];
  const float* b_rel = (const float*)d_in[12];

  const int E = in_sizes[1] / 2;  // 640000
  const int* row = ei;            // source
  const int* col = ei + E;        // target

  char* base = (char*)d_ws;
  size_t off = 0;
  auto alloc = [&](size_t bytes) -> void* {
    void* p = base + off;
    off += (bytes + 255) & ~size_t(255);
    return p;
  };
  int*   cnt     = (int*)  alloc((size_t)N_NODES * 4);
  float* dinv    = (float*)alloc((size_t)N_NODES * 4);
  int*   offs    = (int*)  alloc((size_t)(N_NODES + 1) * 4);
  int*   cursor  = (int*)  alloc((size_t)N_NODES * 4);
  int*   excl    = (int*)  alloc((size_t)N_NODES * 4);
  int*   bsum    = (int*)  alloc((size_t)SCAN_NB * 4);
  int*   csr_src = (int*)  alloc((size_t)E * 4);
  unsigned short* hA = (unsigned short*)alloc((size_t)N_NODES * HID * 2);  // bf16 h
  unsigned short* hB = (unsigned short*)alloc((size_t)N_NODES * HID * 2);  // bf16 g = dinv*hW
  unsigned short* WtAll = (unsigned short*)alloc((size_t)5 * HID * HID * 2); // bf16 W^T x5
  float* pooled  = (float*)alloc((size_t)NGRAPH * HID * 4);
  int*   gstart  = (int*)  alloc((size_t)NGRAPH * 4);
  int*   gend    = (int*)  alloc((size_t)NGRAPH * 4);

  // graph preprocessing
  k_init<<<(N_NODES + 255) / 256, 256, 0, stream>>>(cnt, gstart, gend);
  k_hist<<<(E + 255) / 256, 256, 0, stream>>>(col, E, cnt);
  k_bounds<<<(N_NODES + 255) / 256, 256, 0, stream>>>(batch, gstart, gend);
  k_scan1<<<SCAN_NB, 512, 0, stream>>>(cnt, excl, bsum);
  k_scan2<<<1, 128, 0, stream>>>(bsum, offs);
  k_scan3<<<SCAN_NB, 512, 0, stream>>>(cnt, excl, bsum, offs, cursor, dinv);
  k_fill<<<(E + 255) / 256, 256, 0, stream>>>(row, col, E, cursor, csr_src);
  k_wprep<<<(5 * HID * HID + 255) / 256, 256, 0, stream>>>(W_in, convW, WtAll);

  const int gemm_grid = (N_NODES + 63) / 64;
  // h = relu(x @ W_in + b_in)  (x f32 -> bf16 in-register)
  k_gemm_mfma<true, true, true, false><<<gemm_grid, 256, 0, stream>>>(x, WtAll, b_in, nullptr, hA, N_NODES);

  for (int i = 0; i < NLAYERS; ++i) {
    // g = dinv * (h @ W_i)
    k_gemm_mfma<false, false, false, true><<<gemm_grid, 256, 0, stream>>>(
        hA, WtAll + (size_t)(i + 1) * HID * HID, nullptr, dinv, hB, N_NODES);
    k_agg<<<(N_NODES + 3) / 4, 256, 0, stream>>>(hB, offs, csr_src, dinv, convb + (size_t)i * HID, hA);
  }

  k_pool<<<NGRAPH, 1024, 0, stream>>>(hA, gstart, gend, pooled);
  k_heads<<<dim3(NGRAPH, 3), HID, 0, stream>>>(pooled, W_def, b_def, W_syn, b_syn, W_rel, b_rel,
                                               (float*)d_out);
}